// Round 13
// baseline (321.150 us; speedup 1.0000x reference)
//
#include <hip/hip_runtime.h>
#include <stdint.h>

#define FEAT 256
#define CODES 8192
#define NQ 16384                 // 16*32*32
#define ZQ_ELEMS (NQ * FEAT)
#define MARGIN 2e-3f             // = 2e bound on fp16 score error (R4-validated)
#define RM_ERR 1.0e-3f           // fp16 RNE storage err bound for |rm| < 2
#define NSLICE 8
#define CAP_PAIRS (1 << 18)      // 256K (fallback path only)
#define KSC (-0.0078125f)        // descale: acc * -2/256
#define MEMO_OFF 31457280ull     // 30 MiB: right after fixed ws region
#define MEMO_BYTES 67108864ull   // 64 MiB fp16 group-mins
#define GEMM_BLKS ((NQ / 128) * NSLICE)   // 1024
#define ZN_BLKS (NQ / 16)                 // 1024 (folded into gemm launch)

typedef _Float16 f16x8 __attribute__((ext_vector_type(8)));
typedef float f32x4 __attribute__((ext_vector_type(4)));

__device__ __forceinline__ void async_lds16(void* lds, const void* g) {
  __builtin_amdgcn_global_load_lds(
      (const __attribute__((address_space(1))) void*)(uintptr_t)(g),
      (__attribute__((address_space(3))) void*)(uint32_t)(uintptr_t)(lds),
      16, 0, 0);
}

// monotone float<->uint order transform
__device__ __forceinline__ unsigned f2mono(float v) {
  unsigned u = __float_as_uint(v);
  return (u & 0x80000000u) ? ~u : (u | 0x80000000u);
}
__device__ __forceinline__ float mono2f(unsigned t) {
  unsigned u = (t & 0x80000000u) ? (t & 0x7fffffffu) : ~t;
  return __uint_as_float(u);
}
__device__ __forceinline__ unsigned pack_f16x2(float a, float b) {
  unsigned short ha = __builtin_bit_cast(unsigned short, (_Float16)a);
  unsigned short hb = __builtin_bit_cast(unsigned short, (_Float16)b);
  return (unsigned)ha | ((unsigned)hb << 16);
}

// ---------------------------------------------------------------------------
// numpy pairwise sum-of-squares replication (verified R1-R4, absmax 0).
// ---------------------------------------------------------------------------
template <int STRIDE>
__device__ __forceinline__ float pairwise256_sq(const float* __restrict__ base, int lane16) {
  const int h = lane16 >> 3, j = lane16 & 7;
  const float* p = base + (h * 128 + j) * STRIDE;
  float x = p[0];
  float r = __fmul_rn(x, x);
#pragma unroll
  for (int i = 1; i < 16; ++i) {
    float y = p[i * 8 * STRIDE];
    r = __fadd_rn(r, __fmul_rn(y, y));
  }
  r = __fadd_rn(r, __shfl_xor(r, 1, 64));
  r = __fadd_rn(r, __shfl_xor(r, 2, 64));
  r = __fadd_rn(r, __shfl_xor(r, 4, 64));
  float other = __shfl_xor(r, 8, 64);
  float lo = (h == 0) ? r : other;
  float hi = (h == 0) ? other : r;
  return __fadd_rn(lo, hi);
}

// ---------------------------------------------------------------------------
// prep: fused {cbnorm | convA | convB | buffer-init} via block-range dispatch.
// convA emits At in FRAGMENT-LINEAR order (R12-verified, absmax 0).
// blocks [0,512): cbnorm; [512,1536): convA; [1536,2048): convB;
// [2048,2112): init gmin/packed/paircount.
// ---------------------------------------------------------------------------
#define PREP_BLOCKS 2112
__global__ __launch_bounds__(256) void prep(const float* __restrict__ cb,
                                            const float* __restrict__ z,
                                            float* __restrict__ cbnorm,
                                            char* __restrict__ At, float* __restrict__ zT,
                                            char* __restrict__ Bt,
                                            unsigned* __restrict__ gmin,
                                            unsigned long long* __restrict__ packed,
                                            int* __restrict__ paircount) {
  __shared__ __align__(16) char smem[128 * 40 * 2 + 128 * 36 * 4];
  const int bb0 = blockIdx.x;
  const int t = threadIdx.x;
  if (bb0 < 512) {
    // ---- cbnorm ----
    const int g = (bb0 * 256 + t) >> 4;   // [0, 8192)
    const int lane16 = t & 15;
    float v = pairwise256_sq<1>(cb + g * FEAT, lane16);
    if (lane16 == 0) cbnorm[g] = v;
  } else if (bb0 < 1536) {
    // ---- convA ----
    _Float16* T = (_Float16*)smem;
    float* Tf = (float*)(smem + 128 * 40 * 2);
    const int blk = bb0 - 512;
    const int mt = blk >> 3, ct = blk & 7;
    const int q0 = mt * 128, bb = q0 >> 10, hw0 = q0 & 1023;
    const int c0 = ct * 32;
#pragma unroll
    for (int it = 0; it < 16; ++it) {
      const int cc = it * 2 + (t >> 7);
      const int qi = t & 127;
      float v = z[bb * (FEAT * 1024) + (c0 + cc) * 1024 + hw0 + qi];
      T[qi * 40 + cc] = (_Float16)v;
      Tf[qi * 36 + cc] = v;
    }
    __syncthreads();
    // fragment-linear At: thread t emits fragments f = 2t, 2t+1
#pragma unroll
    for (int g2 = 0; g2 < 2; ++g2) {
      const int f = t * 2 + g2;
      const int fwm = f >> 8, fi = (f >> 6) & 3, fl = f & 63;
      const int row = fwm * 64 + fi * 16 + (fl & 15);
      const int kg = fl >> 4;
      const float4 frag = *(const float4*)&T[row * 40 + kg * 8];
      *(float4*)(At + (size_t)(mt * 8 + ct) * 8192 + (size_t)f * 16) = frag;
    }
    const int r = t >> 1, h = t & 1;
    float* zrow = zT + (size_t)(q0 + r) * FEAT + c0 + h * 16;
#pragma unroll
    for (int e = 0; e < 4; ++e)
      *(float4*)(zrow + e * 4) = *(const float4*)&Tf[r * 36 + h * 16 + e * 4];
  } else if (bb0 < 2048) {
    // ---- convB (fragment-linear fp16, x256; verified R1-R12) ----
    const int T4 = (bb0 - 1536) * 256 + t;   // [0, 131072)
    const int K = T4 >> 4, part = T4 & 15;
    const float* src = cb + (size_t)K * FEAT + part * 16;
    const int nt = K >> 7, rem = K & 127;
    const int wn = rem >> 6, j = (rem >> 4) & 3, llo = rem & 15;
#pragma unroll
    for (int g = 0; g < 2; ++g) {
      const int c0 = part * 16 + g * 8;
      const int ct = c0 >> 5, lhi = (c0 >> 3) & 3;
      const int cg = nt * 8 + ct;
      f16x8 o;
#pragma unroll
      for (int e = 0; e < 8; ++e) o[e] = (_Float16)(src[g * 8 + e] * 256.0f);
      const size_t s = ((size_t)((cg * 2 + wn) * 4 + j) << 6) + (size_t)(lhi * 16 + llo);
      *(f16x8*)(Bt + s * 16) = o;
    }
  } else {
    // ---- init ----
    const int bi = bb0 - 2048;
    const int idx = bi * 256 + t;   // [0, 16384)
    gmin[idx] = 0xFFFFFFFFu;
    packed[idx] = ~0ull;
    if (bi == 0 && t < 64) paircount[t] = 0;
  }
}

// ---------------------------------------------------------------------------
// znorm body: znorm[q] from the contiguous transposed copy zT (bit-identical
// op order to the original strided read -- verified R11/R12, absmax 0).
// ---------------------------------------------------------------------------
__device__ __forceinline__ void znorm_body(const float* __restrict__ zT,
                                           float* __restrict__ znorm,
                                           int zblk, int t) {
  const int q = (zblk * 256 + t) >> 4;   // [0, 16384)
  const int lane16 = t & 15;
  float v = pairwise256_sq<1>(zT + (size_t)q * FEAT, lane16);
  if (lane16 == 0) znorm[q] = v;
}

__global__ __launch_bounds__(256) void znorm_zt(const float* __restrict__ zT,
                                                float* __restrict__ znorm) {
  znorm_body(zT, znorm, blockIdx.x, threadIdx.x);
}

// ---------------------------------------------------------------------------
// GEMM body (R13): A in registers (R12-verified), 4-slot B ring, depth-3
// counted vmcnt(4), ONE barrier/chunk. NEW: the lgkmcnt(0) drain moved AFTER
// the MFMAs -- the compiler now emits fine-grained lgkmcnt(N) between the
// ds_reads and each consuming MFMA (m97 behavior), overlapping ds_read
// latency with MFMA issue. The trailing lgkmcnt(0) is nearly free (reads
// already consumed) and guarantees every ds_read RETIRES before the barrier
// (raw s_barrier does not drain; slot-reuse safety per rule #18 even if an
// MFMA sinks past the barrier). sched_barrier(0) after s_barrier pins next
// chunk's loads after the barrier. Operand values and MFMA order unchanged
// -> identical acc -> absmax 0.
// PASS=0: per-row running min -> atomicMin gmin[q].
// PASS=1: (fallback pass2) push (q<<13|k) for score <= gmin[q]+MARGIN.
// PASS=3: PASS0 + store per-(row,tile) 4-k group-min as packed fp16x2
//         (memo layout identical to R9-R12, scan_exact-verified).
// ---------------------------------------------------------------------------
template <int PASS>
__device__ __forceinline__ void gemm_body(const char* __restrict__ At,
                                          const char* __restrict__ Bt,
                                          const float* __restrict__ cbnorm,
                                          unsigned* __restrict__ gmin,
                                          unsigned* __restrict__ pairs,
                                          int* __restrict__ paircount,
                                          unsigned* __restrict__ memo) {
  __shared__ __align__(16) char Bs[4][8192];   // 4-slot ring, 32 KB

  const int tid = threadIdx.x;
  const int slice = blockIdx.x & 7, mt = blockIdx.x >> 3;
  const int wave = tid >> 6, lane = tid & 63;
  const int wm = wave >> 1, wn = wave & 1;
  const int col = lane & 15, quad = lane >> 4;

  const char* Abase = At + (size_t)(mt * 8) * 8192;
  const char* Bslice = Bt + (size_t)slice * 524288;

  int qrow[16];
#pragma unroll
  for (int row = 0; row < 16; ++row)
    qrow[row] = mt * 128 + wm * 64 + (row >> 2) * 16 + quad * 4 + (row & 3);

  float vmin[16], thr[16];
#pragma unroll
  for (int row = 0; row < 16; ++row) vmin[row] = 3.4e38f;
  if (PASS == 1) {
#pragma unroll
    for (int row = 0; row < 16; ++row) thr[row] = mono2f(gmin[qrow[row]]) + MARGIN;
  }

  // ---- A fragments -> registers (coalesced dwordx4; fully static indexing)
  f16x8 af[8][4];
#pragma unroll
  for (int ct = 0; ct < 8; ++ct)
#pragma unroll
    for (int i = 0; i < 4; ++i)
      af[ct][i] = *(const f16x8*)(Abase + (size_t)ct * 8192 +
                                  (size_t)(wm * 256 + i * 64 + lane) * 16);

#define STAGE_B(SLOT, CIDX)                                                         \
  do {                                                                              \
    const char* gs_ = Bslice + ((size_t)(CIDX) << 13) + wave * 2048 + lane * 16;    \
    async_lds16(Bs[SLOT] + wave * 2048, gs_);                                       \
    async_lds16(Bs[SLOT] + wave * 2048 + 1024, gs_ + 1024);                         \
  } while (0)

  // prologue: prime 3 slots (depth-3 pipeline)
  STAGE_B(0, 0);
  STAGE_B(1, 1);
  STAGE_B(2, 2);
  asm volatile("s_waitcnt vmcnt(4)" ::: "memory");  // af + stage0 complete
  __builtin_amdgcn_sched_barrier(0);
  __builtin_amdgcn_s_barrier();
  __builtin_amdgcn_sched_barrier(0);

  f32x4 acc[4][4];

  // Per-chunk step (global chunk c = nt*8 + CT; buf slot = CT&3 since 8%4==0).
  // WMODE 4: vmcnt(4) -> stage(c+1) complete (newest 4 ops = stages c+2,c+3).
  // 2/0: drain tail. 3: no wait (final chunk).
#define CHUNK(CT, STG, CNEXT, WMODE)                                                \
  do {                                                                              \
    f16x8 bf_[4];                                                                   \
    _Pragma("unroll") for (int j = 0; j < 4; ++j)                                   \
        bf_[j] = *(const f16x8*)(Bs[(CT) & 3] + wn * 4096 + j * 1024 + lane * 16);  \
    if (STG) {                                                                      \
      STAGE_B((CNEXT) & 3, CNEXT);                                                  \
      __builtin_amdgcn_sched_barrier(0);                                            \
    }                                                                               \
    _Pragma("unroll") for (int i = 0; i < 4; ++i)                                   \
        _Pragma("unroll") for (int j = 0; j < 4; ++j)                               \
            acc[i][j] = __builtin_amdgcn_mfma_f32_16x16x32_f16(af[CT][i], bf_[j],   \
                                                               acc[i][j], 0, 0, 0); \
    asm volatile("s_waitcnt lgkmcnt(0)" ::: "memory"); /* retire ds_reads */        \
    __builtin_amdgcn_sched_barrier(0);                                              \
    if ((WMODE) == 4) {                                                             \
      asm volatile("s_waitcnt vmcnt(4)" ::: "memory");                              \
      __builtin_amdgcn_sched_barrier(0);                                            \
    }                                                                               \
    if ((WMODE) == 2) {                                                             \
      asm volatile("s_waitcnt vmcnt(2)" ::: "memory");                              \
      __builtin_amdgcn_sched_barrier(0);                                            \
    }                                                                               \
    if ((WMODE) == 0) {                                                             \
      asm volatile("s_waitcnt vmcnt(0)" ::: "memory");                              \
      __builtin_amdgcn_sched_barrier(0);                                            \
    }                                                                               \
    __builtin_amdgcn_s_barrier();                                                   \
    __builtin_amdgcn_sched_barrier(0);                                              \
  } while (0)

#define ZEROACC                                                                     \
  do {                                                                              \
    _Pragma("unroll") for (int i = 0; i < 4; ++i)                                   \
        _Pragma("unroll") for (int j = 0; j < 4; ++j)                               \
            acc[i][j] = (f32x4){0.f, 0.f, 0.f, 0.f};                                \
  } while (0)

#define SCORING(NT)                                                                 \
  do {                                                                              \
    const int k0_ = (slice * 8 + (NT)) * 128;                                       \
    float cn_[4];                                                                   \
    _Pragma("unroll") for (int j = 0; j < 4; ++j)                                   \
        cn_[j] = cbnorm[k0_ + wn * 64 + j * 16 + col];                              \
    unsigned* sb_ = (PASS == 3)                                                     \
        ? memo + ((((unsigned)blockIdx.x * 8u + (unsigned)(NT)) * 4u +              \
                   (unsigned)wave) * 8u) * 64u + (unsigned)lane                     \
        : nullptr;                                                                  \
    float prev_ = 0.f;                                                              \
    _Pragma("unroll") for (int i = 0; i < 4; ++i)                                   \
        _Pragma("unroll") for (int r = 0; r < 4; ++r) {                             \
      const int row_ = i * 4 + r;                                                   \
      const float s0_ = __builtin_fmaf(acc[i][0][r], KSC, cn_[0]);                  \
      const float s1_ = __builtin_fmaf(acc[i][1][r], KSC, cn_[1]);                  \
      const float s2_ = __builtin_fmaf(acc[i][2][r], KSC, cn_[2]);                  \
      const float s3_ = __builtin_fmaf(acc[i][3][r], KSC, cn_[3]);                  \
      const float rm_ = fminf(fminf(s0_, s1_), fminf(s2_, s3_));                    \
      if (PASS != 1) {                                                              \
        vmin[row_] = fminf(vmin[row_], rm_);                                        \
        if (PASS == 3) {                                                            \
          if ((r & 1) == 0) prev_ = rm_;                                            \
          else sb_[(unsigned)((i * 2 + (r >> 1)) * 64)] = pack_f16x2(prev_, rm_);   \
        }                                                                           \
      } else if (rm_ <= thr[row_]) { /* exact early-out: min_j > thr => none */     \
        const float sv_[4] = {s0_, s1_, s2_, s3_};                                  \
        _Pragma("unroll") for (int j = 0; j < 4; ++j) {                             \
          if (sv_[j] <= thr[row_]) {                                                \
            const int slot_ = atomicAdd(paircount, 1);                              \
            if (slot_ < CAP_PAIRS)                                                  \
              pairs[slot_] = ((unsigned)qrow[row_] << 13) |                         \
                             (unsigned)(k0_ + wn * 64 + j * 16 + col);              \
          }                                                                         \
        }                                                                           \
      }                                                                             \
    }                                                                               \
  } while (0)

  for (int nt = 0; nt < 7; ++nt) {
    ZEROACC;
#pragma unroll
    for (int ct = 0; ct < 8; ++ct) CHUNK(ct, true, nt * 8 + ct + 3, 4);
    SCORING(nt);
  }
  // nt = 7 epilogue: last stage is chunk 60 -> 63; then drain tail
  ZEROACC;
  CHUNK(0, true, 59, 4);
  CHUNK(1, true, 60, 4);
  CHUNK(2, true, 61, 4);
  CHUNK(3, true, 62, 4);
  CHUNK(4, true, 63, 4);
  CHUNK(5, false, 0, 2);
  CHUNK(6, false, 0, 0);
  CHUNK(7, false, 0, 3);
  SCORING(7);

#undef STAGE_B
#undef CHUNK
#undef ZEROACC
#undef SCORING

  if (PASS != 1) {
    // cross-col min (value only), then atomicMin per row
#pragma unroll
    for (int row = 0; row < 16; ++row) {
      float v = vmin[row];
      v = fminf(v, __shfl_xor(v, 1, 64));
      v = fminf(v, __shfl_xor(v, 2, 64));
      v = fminf(v, __shfl_xor(v, 4, 64));
      v = fminf(v, __shfl_xor(v, 8, 64));
      if (col == 0) atomicMin(&gmin[qrow[row]], f2mono(v));
    }
  }
}

__global__ __launch_bounds__(256, 2) void gemm_pass1(const char* __restrict__ At,
                                                     const char* __restrict__ Bt,
                                                     const float* __restrict__ cbnorm,
                                                     unsigned* __restrict__ gmin) {
  gemm_body<0>(At, Bt, cbnorm, gmin, nullptr, nullptr, nullptr);
}

// memo-path GEMM with znorm blocks folded in (blocks >= GEMM_BLKS run znorm)
__global__ __launch_bounds__(256, 4) void gemm_pass1m(const char* __restrict__ At,
                                                      const char* __restrict__ Bt,
                                                      const float* __restrict__ cbnorm,
                                                      unsigned* __restrict__ gmin,
                                                      unsigned* __restrict__ memo,
                                                      const float* __restrict__ zT,
                                                      float* __restrict__ znorm) {
  if ((int)blockIdx.x >= GEMM_BLKS) {
    znorm_body(zT, znorm, (int)blockIdx.x - GEMM_BLKS, threadIdx.x);
    return;
  }
  gemm_body<3>(At, Bt, cbnorm, gmin, nullptr, nullptr, memo);
}

__global__ __launch_bounds__(256, 2) void gemm_pass2(const char* __restrict__ At,
                                                     const char* __restrict__ Bt,
                                                     const float* __restrict__ cbnorm,
                                                     unsigned* __restrict__ gmin,
                                                     unsigned* __restrict__ pairs,
                                                     int* __restrict__ paircount) {
  gemm_body<1>(At, Bt, cbnorm, gmin, pairs, paircount, nullptr);
}

// ---------------------------------------------------------------------------
// scan_exact: stream the 64 MiB fp16 group-min memo (decode R9-R12 verified);
// for each hit (stored rm <= gmin[q]+MARGIN+RM_ERR), the whole wave rescores
// the 4-k group with the R4-verified exact fp32 chain and atomicMin's the
// per-q winner. Per-lane hit bitmask; wave-coop loop via ballot/ffs/shfl.
// id encoding: (q << 11) | (ntile << 5) | (wn << 4) | col.
// ---------------------------------------------------------------------------
__global__ __launch_bounds__(256) void scan_exact(const unsigned* __restrict__ memo,
                                                  const unsigned* __restrict__ gmin,
                                                  const float* __restrict__ zT,
                                                  const float* __restrict__ cb,
                                                  const float* __restrict__ cbnorm,
                                                  const float* __restrict__ znorm,
                                                  unsigned long long* __restrict__ packed) {
  const unsigned NU4 = 4194304u;  // 64 MiB / 16
  const unsigned stride = gridDim.x * blockDim.x;  // 524288 divides NU4: uniform trip count
  const int lane = threadIdx.x & 63;
  for (unsigned U = blockIdx.x * 256 + threadIdx.x; U < NU4; U += stride) {
    const uint4 v = ((const uint4*)memo)[U];
    const unsigned u = U << 2;
    const unsigned lane0 = u & 63, col0 = lane0 & 15, quad = lane0 >> 4;
    const unsigned rp = (u >> 6) & 7;
    const unsigned w = (u >> 9) & 3;
    const unsigned t = (u >> 11) & 7;
    const unsigned blk = u >> 14;
    const unsigned mt = blk >> 3, slice = blk & 7;
    const unsigned wm = w >> 1, wn = w & 1;
    const unsigned ntile = slice * 8u + t;
    const unsigned row0 = rp * 2u;
    const int q0 = (int)(mt * 128u + wm * 64u + (row0 >> 2) * 16u + quad * 4u + (row0 & 3u));
    const float thr0 = mono2f(gmin[q0]) + (MARGIN + RM_ERR);
    const float thr1 = mono2f(gmin[q0 + 1]) + (MARGIN + RM_ERR);
    const unsigned wv[4] = {v.x, v.y, v.z, v.w};
    unsigned hm = 0;  // bit = wi*2 + h  (h=0 -> q0, h=1 -> q0+1)
#pragma unroll
    for (int wi = 0; wi < 4; ++wi) {
      const float lo = (float)__builtin_bit_cast(_Float16, (unsigned short)(wv[wi] & 0xffffu));
      const float hi = (float)__builtin_bit_cast(_Float16, (unsigned short)(wv[wi] >> 16));
      if (lo <= thr0) hm |= 1u << (wi * 2);
      if (hi <= thr1) hm |= 1u << (wi * 2 + 1);
    }
    // wave-cooperative rescore of each hit (rare: ~19K hits / 33.5M groups)
    while (true) {
      const unsigned long long act = __ballot(hm != 0);
      if (!act) break;
      const int src = (int)(__ffsll((unsigned long long)act) - 1);
      unsigned myid = 0;
      {
        const int bit = __ffs((int)hm) - 1;
        if (bit >= 0) {
          const unsigned wi = (unsigned)bit >> 1, h = (unsigned)bit & 1;
          const unsigned kid = (ntile << 5) | (wn << 4) | (col0 + wi);
          myid = ((unsigned)(q0 + (int)h) << 11) | kid;
        }
      }
      const unsigned id = (unsigned)__shfl((int)myid, src, 64);
      const int q = (int)(id >> 11);
      const int base = (int)(((id >> 5) & 63u) * 128u + ((id >> 4) & 1u) * 64u + (id & 15u));
      const float4 zv = ((const float4*)(zT + (size_t)q * FEAT))[lane];
      const float zn = znorm[q];
      unsigned long long best = ~0ull;
#pragma unroll
      for (int j = 0; j < 4; ++j) {
        const int k = base + j * 16;
        const float4 cv = ((const float4*)(cb + (size_t)k * FEAT))[lane];
        float d = __builtin_fmaf(zv.w, cv.w,
                  __builtin_fmaf(zv.z, cv.z,
                  __builtin_fmaf(zv.y, cv.y, __fmul_rn(zv.x, cv.x))));
#pragma unroll
        for (int dd = 1; dd < 64; dd <<= 1) d = __fadd_rn(d, __shfl_xor(d, dd, 64));
        const float s = __fadd_rn(__fadd_rn(__fmul_rn(-2.0f, d), zn), cbnorm[k]);
        const unsigned long long key = ((unsigned long long)f2mono(s) << 32) | (unsigned)k;
        best = (key < best) ? key : best;
      }
      if (lane == 0) atomicMin(&packed[q], best);
      if (lane == src) hm &= hm - 1;  // clear processed hit
    }
  }
}

// ---------------------------------------------------------------------------
// Exact fp32 rescore of (q,k) pairs (fallback path, R4-verified machinery).
// ---------------------------------------------------------------------------
__global__ __launch_bounds__(256) void exact_cand(const float* __restrict__ zT,
                                                  const float* __restrict__ cb,
                                                  const float* __restrict__ cbnorm,
                                                  const float* __restrict__ znorm,
                                                  const unsigned* __restrict__ pairs,
                                                  const int* __restrict__ paircount,
                                                  unsigned long long* __restrict__ packed) {
  const int cnt = min(*paircount, CAP_PAIRS);
  const int gw = (blockIdx.x * 256 + threadIdx.x) >> 6;
  const int nw = (gridDim.x * 256) >> 6;
  const int lane = threadIdx.x & 63;
  for (int p = gw; p < cnt; p += nw) {
    const unsigned qk = pairs[p];
    const int q = qk >> 13, k = qk & 8191;
    const float4 cv = ((const float4*)(cb + (size_t)k * FEAT))[lane];
    const float4 zv = ((const float4*)(zT + (size_t)q * FEAT))[lane];
    float d = __builtin_fmaf(zv.w, cv.w,
              __builtin_fmaf(zv.z, cv.z,
              __builtin_fmaf(zv.y, cv.y, __fmul_rn(zv.x, cv.x))));
#pragma unroll
    for (int dd = 1; dd < 64; dd <<= 1) d = __fadd_rn(d, __shfl_xor(d, dd, 64));
    const float s = __fadd_rn(__fadd_rn(__fmul_rn(-2.0f, d), znorm[q]), cbnorm[k]);
    if (lane == 0) {
      const unsigned long long key = ((unsigned long long)f2mono(s) << 32) | (unsigned)k;
      atomicMin(&packed[q], key);
    }
  }
}

// ---------------------------------------------------------------------------
// Gather: zq[b][c][hw] = cb[idx]; idx as float appended after zq.
// ---------------------------------------------------------------------------
__global__ __launch_bounds__(256) void vq_gather(const float* __restrict__ cb,
                                                 const unsigned long long* __restrict__ packed,
                                                 float* __restrict__ out) {
  const int q0 = blockIdx.x * 64;
  const int nl = threadIdx.x & 63;
  const int cg = threadIdx.x >> 6;
  const int q = q0 + nl;
  const int kq = (int)((unsigned)packed[q] & 8191u);
  const int b = q >> 10, hw = q & 1023;
  const float4* cb4 = (const float4*)cb;
#pragma unroll
  for (int t = 0; t < 16; ++t) {
    const int cc = cg + t * 4;
    const float4 v = cb4[kq * 64 + cc];
    const int base = b * (FEAT * 1024) + (cc * 4) * 1024 + hw;
    out[base] = v.x;
    out[base + 1024] = v.y;
    out[base + 2048] = v.z;
    out[base + 3072] = v.w;
  }
  if (threadIdx.x < 64) {
    const int qq = q0 + threadIdx.x;
    out[ZQ_ELEMS + qq] = (float)(int)((unsigned)packed[qq] & 8191u);
  }
}

extern "C" void kernel_launch(void* const* d_in, const int* in_sizes, int n_in,
                              void* d_out, int out_size, void* d_ws, size_t ws_size,
                              hipStream_t stream) {
  const float* z = (const float*)d_in[0];
  const float* cb = (const float*)d_in[1];
  char* w = (char*)d_ws;
  // ws layout: ~30 MiB fixed + 64 MiB group-min memo at MEMO_OFF
  char* At = w;                                            // 8 MB
  char* Bt = w + 8388608;                                  // 4 MB
  float* zT = (float*)(w + 12582912);                      // 16 MB
  float* cbnorm = (float*)(w + 29360128);                  // 32 KB
  float* znorm = (float*)(w + 29392896);                   // 64 KB
  unsigned* gmin = (unsigned*)(w + 29458432);              // 64 KB
  int* paircount = (int*)(w + 29523968);                   // 256 B
  unsigned* pairs = (unsigned*)(w + 29524224);             // 1 MB (fallback only)
  unsigned long long* packed = (unsigned long long*)(w + 30572800);  // 128 KB
  unsigned* memo = (unsigned*)(w + MEMO_OFF);              // 64 MiB fp16 group-mins

  const bool use_memo = ws_size >= (size_t)(MEMO_OFF + MEMO_BYTES);

  prep<<<PREP_BLOCKS, 256, 0, stream>>>(cb, z, cbnorm, At, zT, Bt,
                                        gmin, packed, paircount);
  if (use_memo) {
    gemm_pass1m<<<GEMM_BLKS + ZN_BLKS, 256, 0, stream>>>(At, Bt, cbnorm, gmin, memo, zT, znorm);
    scan_exact<<<2048, 256, 0, stream>>>(memo, gmin, zT, cb, cbnorm, znorm, packed);
  } else {
    znorm_zt<<<NQ / 16, 256, 0, stream>>>(zT, znorm);
    gemm_pass1<<<GEMM_BLKS, 256, 0, stream>>>(At, Bt, cbnorm, gmin);
    gemm_pass2<<<GEMM_BLKS, 256, 0, stream>>>(At, Bt, cbnorm, gmin, pairs, paircount);
    exact_cand<<<512, 256, 0, stream>>>(zT, cb, cbnorm, znorm, pairs, paircount, packed);
  }
  vq_gather<<<NQ / 64, 256, 0, stream>>>(cb, packed, (float*)d_out);
}

// Round 14
// 180.254 us; speedup vs baseline: 1.7817x; 1.7817x over previous
//
#include <hip/hip_runtime.h>
#include <stdint.h>

#define FEAT 256
#define CODES 8192
#define NQ 16384                 // 16*32*32
#define ZQ_ELEMS (NQ * FEAT)
#define MARGIN 2e-3f             // = 2e bound on fp16 score error (R4-validated)
#define RM_ERR 1.0e-3f           // fp16 RNE storage err bound for |rm| < 2
#define NSLICE 8
#define CAP_PAIRS (1 << 18)      // 256K (fallback path only)
#define KSC (-0.0078125f)        // descale: acc * -2/256
#define MEMO_OFF 31457280ull     // 30 MiB: right after fixed ws region
#define MEMO_BYTES 67108864ull   // 64 MiB fp16 group-mins
#define GEMM_BLKS ((NQ / 128) * NSLICE)   // 1024
#define ZN_BLKS (NQ / 16)                 // 1024 (folded into gemm launch)

typedef _Float16 f16x8 __attribute__((ext_vector_type(8)));
typedef float f32x4 __attribute__((ext_vector_type(4)));

__device__ __forceinline__ void async_lds16(void* lds, const void* g) {
  __builtin_amdgcn_global_load_lds(
      (const __attribute__((address_space(1))) void*)(uintptr_t)(g),
      (__attribute__((address_space(3))) void*)(uint32_t)(uintptr_t)(lds),
      16, 0, 0);
}

// monotone float<->uint order transform
__device__ __forceinline__ unsigned f2mono(float v) {
  unsigned u = __float_as_uint(v);
  return (u & 0x80000000u) ? ~u : (u | 0x80000000u);
}
__device__ __forceinline__ float mono2f(unsigned t) {
  unsigned u = (t & 0x80000000u) ? (t & 0x7fffffffu) : ~t;
  return __uint_as_float(u);
}
__device__ __forceinline__ unsigned pack_f16x2(float a, float b) {
  unsigned short ha = __builtin_bit_cast(unsigned short, (_Float16)a);
  unsigned short hb = __builtin_bit_cast(unsigned short, (_Float16)b);
  return (unsigned)ha | ((unsigned)hb << 16);
}

// ---------------------------------------------------------------------------
// numpy pairwise sum-of-squares replication (verified R1-R4, absmax 0).
// ---------------------------------------------------------------------------
template <int STRIDE>
__device__ __forceinline__ float pairwise256_sq(const float* __restrict__ base, int lane16) {
  const int h = lane16 >> 3, j = lane16 & 7;
  const float* p = base + (h * 128 + j) * STRIDE;
  float x = p[0];
  float r = __fmul_rn(x, x);
#pragma unroll
  for (int i = 1; i < 16; ++i) {
    float y = p[i * 8 * STRIDE];
    r = __fadd_rn(r, __fmul_rn(y, y));
  }
  r = __fadd_rn(r, __shfl_xor(r, 1, 64));
  r = __fadd_rn(r, __shfl_xor(r, 2, 64));
  r = __fadd_rn(r, __shfl_xor(r, 4, 64));
  float other = __shfl_xor(r, 8, 64);
  float lo = (h == 0) ? r : other;
  float hi = (h == 0) ? other : r;
  return __fadd_rn(lo, hi);
}

// ---------------------------------------------------------------------------
// prep: fused {cbnorm | convA | convB | buffer-init} via block-range dispatch.
// convA emits At in FRAGMENT-LINEAR order (R12-verified, absmax 0).
// blocks [0,512): cbnorm; [512,1536): convA; [1536,2048): convB;
// [2048,2112): init gmin/packed/paircount.
// ---------------------------------------------------------------------------
#define PREP_BLOCKS 2112
__global__ __launch_bounds__(256) void prep(const float* __restrict__ cb,
                                            const float* __restrict__ z,
                                            float* __restrict__ cbnorm,
                                            char* __restrict__ At, float* __restrict__ zT,
                                            char* __restrict__ Bt,
                                            unsigned* __restrict__ gmin,
                                            unsigned long long* __restrict__ packed,
                                            int* __restrict__ paircount) {
  __shared__ __align__(16) char smem[128 * 40 * 2 + 128 * 36 * 4];
  const int bb0 = blockIdx.x;
  const int t = threadIdx.x;
  if (bb0 < 512) {
    // ---- cbnorm ----
    const int g = (bb0 * 256 + t) >> 4;   // [0, 8192)
    const int lane16 = t & 15;
    float v = pairwise256_sq<1>(cb + g * FEAT, lane16);
    if (lane16 == 0) cbnorm[g] = v;
  } else if (bb0 < 1536) {
    // ---- convA ----
    _Float16* T = (_Float16*)smem;
    float* Tf = (float*)(smem + 128 * 40 * 2);
    const int blk = bb0 - 512;
    const int mt = blk >> 3, ct = blk & 7;
    const int q0 = mt * 128, bb = q0 >> 10, hw0 = q0 & 1023;
    const int c0 = ct * 32;
#pragma unroll
    for (int it = 0; it < 16; ++it) {
      const int cc = it * 2 + (t >> 7);
      const int qi = t & 127;
      float v = z[bb * (FEAT * 1024) + (c0 + cc) * 1024 + hw0 + qi];
      T[qi * 40 + cc] = (_Float16)v;
      Tf[qi * 36 + cc] = v;
    }
    __syncthreads();
    // fragment-linear At: thread t emits fragments f = 2t, 2t+1
#pragma unroll
    for (int g2 = 0; g2 < 2; ++g2) {
      const int f = t * 2 + g2;
      const int fwm = f >> 8, fi = (f >> 6) & 3, fl = f & 63;
      const int row = fwm * 64 + fi * 16 + (fl & 15);
      const int kg = fl >> 4;
      const float4 frag = *(const float4*)&T[row * 40 + kg * 8];
      *(float4*)(At + (size_t)(mt * 8 + ct) * 8192 + (size_t)f * 16) = frag;
    }
    const int r = t >> 1, h = t & 1;
    float* zrow = zT + (size_t)(q0 + r) * FEAT + c0 + h * 16;
#pragma unroll
    for (int e = 0; e < 4; ++e)
      *(float4*)(zrow + e * 4) = *(const float4*)&Tf[r * 36 + h * 16 + e * 4];
  } else if (bb0 < 2048) {
    // ---- convB (fragment-linear fp16, x256; verified R1-R13) ----
    const int T4 = (bb0 - 1536) * 256 + t;   // [0, 131072)
    const int K = T4 >> 4, part = T4 & 15;
    const float* src = cb + (size_t)K * FEAT + part * 16;
    const int nt = K >> 7, rem = K & 127;
    const int wn = rem >> 6, j = (rem >> 4) & 3, llo = rem & 15;
#pragma unroll
    for (int g = 0; g < 2; ++g) {
      const int c0 = part * 16 + g * 8;
      const int ct = c0 >> 5, lhi = (c0 >> 3) & 3;
      const int cg = nt * 8 + ct;
      f16x8 o;
#pragma unroll
      for (int e = 0; e < 8; ++e) o[e] = (_Float16)(src[g * 8 + e] * 256.0f);
      const size_t s = ((size_t)((cg * 2 + wn) * 4 + j) << 6) + (size_t)(lhi * 16 + llo);
      *(f16x8*)(Bt + s * 16) = o;
    }
  } else {
    // ---- init ----
    const int bi = bb0 - 2048;
    const int idx = bi * 256 + t;   // [0, 16384)
    gmin[idx] = 0xFFFFFFFFu;
    packed[idx] = ~0ull;
    if (bi == 0 && t < 64) paircount[t] = 0;
  }
}

// ---------------------------------------------------------------------------
// znorm body: znorm[q] from the contiguous transposed copy zT (bit-identical
// op order to the original strided read -- verified R11-R13, absmax 0).
// ---------------------------------------------------------------------------
__device__ __forceinline__ void znorm_body(const float* __restrict__ zT,
                                           float* __restrict__ znorm,
                                           int zblk, int t) {
  const int q = (zblk * 256 + t) >> 4;   // [0, 16384)
  const int lane16 = t & 15;
  float v = pairwise256_sq<1>(zT + (size_t)q * FEAT, lane16);
  if (lane16 == 0) znorm[q] = v;
}

__global__ __launch_bounds__(256) void znorm_zt(const float* __restrict__ zT,
                                                float* __restrict__ znorm) {
  znorm_body(zT, znorm, blockIdx.x, threadIdx.x);
}

// ---------------------------------------------------------------------------
// GEMM body (R14 = R12 structure + R13's lgkm-after-MFMA reorder, with the
// VGPR budget RESTORED to launch_bounds(256,2) -- R13's (256,4) capped the
// wave at 128 VGPRs, spilling the 128-VGPR A-array to scratch (VGPR_Count
// 64, FETCH 611 MB, 3x regression). A in registers; 4-slot B ring; depth-3
// counted vmcnt(4); ONE barrier/chunk; lgkmcnt(0) AFTER the MFMAs so the
// compiler emits fine-grained lgkmcnt(N) between ds_reads and consuming
// MFMAs. Operand values and MFMA order unchanged -> absmax 0.
// PASS=0: per-row running min -> atomicMin gmin[q].
// PASS=1: (fallback pass2) push (q<<13|k) for score <= gmin[q]+MARGIN.
// PASS=3: PASS0 + store per-(row,tile) 4-k group-min as packed fp16x2
//         (memo layout identical to R9-R13, scan_exact-verified).
// ---------------------------------------------------------------------------
template <int PASS>
__device__ __forceinline__ void gemm_body(const char* __restrict__ At,
                                          const char* __restrict__ Bt,
                                          const float* __restrict__ cbnorm,
                                          unsigned* __restrict__ gmin,
                                          unsigned* __restrict__ pairs,
                                          int* __restrict__ paircount,
                                          unsigned* __restrict__ memo) {
  __shared__ __align__(16) char Bs[4][8192];   // 4-slot ring, 32 KB

  const int tid = threadIdx.x;
  const int slice = blockIdx.x & 7, mt = blockIdx.x >> 3;
  const int wave = tid >> 6, lane = tid & 63;
  const int wm = wave >> 1, wn = wave & 1;
  const int col = lane & 15, quad = lane >> 4;

  const char* Abase = At + (size_t)(mt * 8) * 8192;
  const char* Bslice = Bt + (size_t)slice * 524288;

  int qrow[16];
#pragma unroll
  for (int row = 0; row < 16; ++row)
    qrow[row] = mt * 128 + wm * 64 + (row >> 2) * 16 + quad * 4 + (row & 3);

  float vmin[16], thr[16];
#pragma unroll
  for (int row = 0; row < 16; ++row) vmin[row] = 3.4e38f;
  if (PASS == 1) {
#pragma unroll
    for (int row = 0; row < 16; ++row) thr[row] = mono2f(gmin[qrow[row]]) + MARGIN;
  }

  // ---- A fragments -> registers (coalesced dwordx4; fully static indexing)
  f16x8 af[8][4];
#pragma unroll
  for (int ct = 0; ct < 8; ++ct)
#pragma unroll
    for (int i = 0; i < 4; ++i)
      af[ct][i] = *(const f16x8*)(Abase + (size_t)ct * 8192 +
                                  (size_t)(wm * 256 + i * 64 + lane) * 16);

#define STAGE_B(SLOT, CIDX)                                                         \
  do {                                                                              \
    const char* gs_ = Bslice + ((size_t)(CIDX) << 13) + wave * 2048 + lane * 16;    \
    async_lds16(Bs[SLOT] + wave * 2048, gs_);                                       \
    async_lds16(Bs[SLOT] + wave * 2048 + 1024, gs_ + 1024);                         \
  } while (0)

  // prologue: prime 3 slots (depth-3 pipeline)
  STAGE_B(0, 0);
  STAGE_B(1, 1);
  STAGE_B(2, 2);
  asm volatile("s_waitcnt vmcnt(4)" ::: "memory");  // af + stage0 complete
  __builtin_amdgcn_sched_barrier(0);
  __builtin_amdgcn_s_barrier();
  __builtin_amdgcn_sched_barrier(0);

  f32x4 acc[4][4];

  // Per-chunk step (global chunk c = nt*8 + CT; buf slot = CT&3 since 8%4==0).
  // WMODE 4: vmcnt(4) -> stage(c+1) complete (newest 4 ops = stages c+2,c+3).
  // 2/0: drain tail. 3: no wait (final chunk).
#define CHUNK(CT, STG, CNEXT, WMODE)                                                \
  do {                                                                              \
    f16x8 bf_[4];                                                                   \
    _Pragma("unroll") for (int j = 0; j < 4; ++j)                                   \
        bf_[j] = *(const f16x8*)(Bs[(CT) & 3] + wn * 4096 + j * 1024 + lane * 16);  \
    if (STG) {                                                                      \
      STAGE_B((CNEXT) & 3, CNEXT);                                                  \
      __builtin_amdgcn_sched_barrier(0);                                            \
    }                                                                               \
    _Pragma("unroll") for (int i = 0; i < 4; ++i)                                   \
        _Pragma("unroll") for (int j = 0; j < 4; ++j)                               \
            acc[i][j] = __builtin_amdgcn_mfma_f32_16x16x32_f16(af[CT][i], bf_[j],   \
                                                               acc[i][j], 0, 0, 0); \
    asm volatile("s_waitcnt lgkmcnt(0)" ::: "memory"); /* retire ds_reads */        \
    __builtin_amdgcn_sched_barrier(0);                                              \
    if ((WMODE) == 4) {                                                             \
      asm volatile("s_waitcnt vmcnt(4)" ::: "memory");                              \
      __builtin_amdgcn_sched_barrier(0);                                            \
    }                                                                               \
    if ((WMODE) == 2) {                                                             \
      asm volatile("s_waitcnt vmcnt(2)" ::: "memory");                              \
      __builtin_amdgcn_sched_barrier(0);                                            \
    }                                                                               \
    if ((WMODE) == 0) {                                                             \
      asm volatile("s_waitcnt vmcnt(0)" ::: "memory");                              \
      __builtin_amdgcn_sched_barrier(0);                                            \
    }                                                                               \
    __builtin_amdgcn_s_barrier();                                                   \
    __builtin_amdgcn_sched_barrier(0);                                              \
  } while (0)

#define ZEROACC                                                                     \
  do {                                                                              \
    _Pragma("unroll") for (int i = 0; i < 4; ++i)                                   \
        _Pragma("unroll") for (int j = 0; j < 4; ++j)                               \
            acc[i][j] = (f32x4){0.f, 0.f, 0.f, 0.f};                                \
  } while (0)

#define SCORING(NT)                                                                 \
  do {                                                                              \
    const int k0_ = (slice * 8 + (NT)) * 128;                                       \
    float cn_[4];                                                                   \
    _Pragma("unroll") for (int j = 0; j < 4; ++j)                                   \
        cn_[j] = cbnorm[k0_ + wn * 64 + j * 16 + col];                              \
    unsigned* sb_ = (PASS == 3)                                                     \
        ? memo + ((((unsigned)blockIdx.x * 8u + (unsigned)(NT)) * 4u +              \
                   (unsigned)wave) * 8u) * 64u + (unsigned)lane                     \
        : nullptr;                                                                  \
    float prev_ = 0.f;                                                              \
    _Pragma("unroll") for (int i = 0; i < 4; ++i)                                   \
        _Pragma("unroll") for (int r = 0; r < 4; ++r) {                             \
      const int row_ = i * 4 + r;                                                   \
      const float s0_ = __builtin_fmaf(acc[i][0][r], KSC, cn_[0]);                  \
      const float s1_ = __builtin_fmaf(acc[i][1][r], KSC, cn_[1]);                  \
      const float s2_ = __builtin_fmaf(acc[i][2][r], KSC, cn_[2]);                  \
      const float s3_ = __builtin_fmaf(acc[i][3][r], KSC, cn_[3]);                  \
      const float rm_ = fminf(fminf(s0_, s1_), fminf(s2_, s3_));                    \
      if (PASS != 1) {                                                              \
        vmin[row_] = fminf(vmin[row_], rm_);                                        \
        if (PASS == 3) {                                                            \
          if ((r & 1) == 0) prev_ = rm_;                                            \
          else sb_[(unsigned)((i * 2 + (r >> 1)) * 64)] = pack_f16x2(prev_, rm_);   \
        }                                                                           \
      } else if (rm_ <= thr[row_]) { /* exact early-out: min_j > thr => none */     \
        const float sv_[4] = {s0_, s1_, s2_, s3_};                                  \
        _Pragma("unroll") for (int j = 0; j < 4; ++j) {                             \
          if (sv_[j] <= thr[row_]) {                                                \
            const int slot_ = atomicAdd(paircount, 1);                              \
            if (slot_ < CAP_PAIRS)                                                  \
              pairs[slot_] = ((unsigned)qrow[row_] << 13) |                         \
                             (unsigned)(k0_ + wn * 64 + j * 16 + col);              \
          }                                                                         \
        }                                                                           \
      }                                                                             \
    }                                                                               \
  } while (0)

  for (int nt = 0; nt < 7; ++nt) {
    ZEROACC;
#pragma unroll
    for (int ct = 0; ct < 8; ++ct) CHUNK(ct, true, nt * 8 + ct + 3, 4);
    SCORING(nt);
  }
  // nt = 7 epilogue: last stage is chunk 60 -> 63; then drain tail
  ZEROACC;
  CHUNK(0, true, 59, 4);
  CHUNK(1, true, 60, 4);
  CHUNK(2, true, 61, 4);
  CHUNK(3, true, 62, 4);
  CHUNK(4, true, 63, 4);
  CHUNK(5, false, 0, 2);
  CHUNK(6, false, 0, 0);
  CHUNK(7, false, 0, 3);
  SCORING(7);

#undef STAGE_B
#undef CHUNK
#undef ZEROACC
#undef SCORING

  if (PASS != 1) {
    // cross-col min (value only), then atomicMin per row
#pragma unroll
    for (int row = 0; row < 16; ++row) {
      float v = vmin[row];
      v = fminf(v, __shfl_xor(v, 1, 64));
      v = fminf(v, __shfl_xor(v, 2, 64));
      v = fminf(v, __shfl_xor(v, 4, 64));
      v = fminf(v, __shfl_xor(v, 8, 64));
      if (col == 0) atomicMin(&gmin[qrow[row]], f2mono(v));
    }
  }
}

__global__ __launch_bounds__(256, 2) void gemm_pass1(const char* __restrict__ At,
                                                     const char* __restrict__ Bt,
                                                     const float* __restrict__ cbnorm,
                                                     unsigned* __restrict__ gmin) {
  gemm_body<0>(At, Bt, cbnorm, gmin, nullptr, nullptr, nullptr);
}

// memo-path GEMM with znorm blocks folded in (blocks >= GEMM_BLKS run znorm).
// launch_bounds(256,2): cap 256 VGPR -- R12-proven (128 used, no spill).
__global__ __launch_bounds__(256, 2) void gemm_pass1m(const char* __restrict__ At,
                                                      const char* __restrict__ Bt,
                                                      const float* __restrict__ cbnorm,
                                                      unsigned* __restrict__ gmin,
                                                      unsigned* __restrict__ memo,
                                                      const float* __restrict__ zT,
                                                      float* __restrict__ znorm) {
  if ((int)blockIdx.x >= GEMM_BLKS) {
    znorm_body(zT, znorm, (int)blockIdx.x - GEMM_BLKS, threadIdx.x);
    return;
  }
  gemm_body<3>(At, Bt, cbnorm, gmin, nullptr, nullptr, memo);
}

__global__ __launch_bounds__(256, 2) void gemm_pass2(const char* __restrict__ At,
                                                     const char* __restrict__ Bt,
                                                     const float* __restrict__ cbnorm,
                                                     unsigned* __restrict__ gmin,
                                                     unsigned* __restrict__ pairs,
                                                     int* __restrict__ paircount) {
  gemm_body<1>(At, Bt, cbnorm, gmin, pairs, paircount, nullptr);
}

// ---------------------------------------------------------------------------
// scan_exact: stream the 64 MiB fp16 group-min memo (decode R9-R13 verified);
// for each hit (stored rm <= gmin[q]+MARGIN+RM_ERR), the whole wave rescores
// the 4-k group with the R4-verified exact fp32 chain and atomicMin's the
// per-q winner. Per-lane hit bitmask; wave-coop loop via ballot/ffs/shfl.
// id encoding: (q << 11) | (ntile << 5) | (wn << 4) | col.
// ---------------------------------------------------------------------------
__global__ __launch_bounds__(256) void scan_exact(const unsigned* __restrict__ memo,
                                                  const unsigned* __restrict__ gmin,
                                                  const float* __restrict__ zT,
                                                  const float* __restrict__ cb,
                                                  const float* __restrict__ cbnorm,
                                                  const float* __restrict__ znorm,
                                                  unsigned long long* __restrict__ packed) {
  const unsigned NU4 = 4194304u;  // 64 MiB / 16
  const unsigned stride = gridDim.x * blockDim.x;  // 524288 divides NU4: uniform trip count
  const int lane = threadIdx.x & 63;
  for (unsigned U = blockIdx.x * 256 + threadIdx.x; U < NU4; U += stride) {
    const uint4 v = ((const uint4*)memo)[U];
    const unsigned u = U << 2;
    const unsigned lane0 = u & 63, col0 = lane0 & 15, quad = lane0 >> 4;
    const unsigned rp = (u >> 6) & 7;
    const unsigned w = (u >> 9) & 3;
    const unsigned t = (u >> 11) & 7;
    const unsigned blk = u >> 14;
    const unsigned mt = blk >> 3, slice = blk & 7;
    const unsigned wm = w >> 1, wn = w & 1;
    const unsigned ntile = slice * 8u + t;
    const unsigned row0 = rp * 2u;
    const int q0 = (int)(mt * 128u + wm * 64u + (row0 >> 2) * 16u + quad * 4u + (row0 & 3u));
    const float thr0 = mono2f(gmin[q0]) + (MARGIN + RM_ERR);
    const float thr1 = mono2f(gmin[q0 + 1]) + (MARGIN + RM_ERR);
    const unsigned wv[4] = {v.x, v.y, v.z, v.w};
    unsigned hm = 0;  // bit = wi*2 + h  (h=0 -> q0, h=1 -> q0+1)
#pragma unroll
    for (int wi = 0; wi < 4; ++wi) {
      const float lo = (float)__builtin_bit_cast(_Float16, (unsigned short)(wv[wi] & 0xffffu));
      const float hi = (float)__builtin_bit_cast(_Float16, (unsigned short)(wv[wi] >> 16));
      if (lo <= thr0) hm |= 1u << (wi * 2);
      if (hi <= thr1) hm |= 1u << (wi * 2 + 1);
    }
    // wave-cooperative rescore of each hit (rare: ~19K hits / 33.5M groups)
    while (true) {
      const unsigned long long act = __ballot(hm != 0);
      if (!act) break;
      const int src = (int)(__ffsll((unsigned long long)act) - 1);
      unsigned myid = 0;
      {
        const int bit = __ffs((int)hm) - 1;
        if (bit >= 0) {
          const unsigned wi = (unsigned)bit >> 1, h = (unsigned)bit & 1;
          const unsigned kid = (ntile << 5) | (wn << 4) | (col0 + wi);
          myid = ((unsigned)(q0 + (int)h) << 11) | kid;
        }
      }
      const unsigned id = (unsigned)__shfl((int)myid, src, 64);
      const int q = (int)(id >> 11);
      const int base = (int)(((id >> 5) & 63u) * 128u + ((id >> 4) & 1u) * 64u + (id & 15u));
      const float4 zv = ((const float4*)(zT + (size_t)q * FEAT))[lane];
      const float zn = znorm[q];
      unsigned long long best = ~0ull;
#pragma unroll
      for (int j = 0; j < 4; ++j) {
        const int k = base + j * 16;
        const float4 cv = ((const float4*)(cb + (size_t)k * FEAT))[lane];
        float d = __builtin_fmaf(zv.w, cv.w,
                  __builtin_fmaf(zv.z, cv.z,
                  __builtin_fmaf(zv.y, cv.y, __fmul_rn(zv.x, cv.x))));
#pragma unroll
        for (int dd = 1; dd < 64; dd <<= 1) d = __fadd_rn(d, __shfl_xor(d, dd, 64));
        const float s = __fadd_rn(__fadd_rn(__fmul_rn(-2.0f, d), zn), cbnorm[k]);
        const unsigned long long key = ((unsigned long long)f2mono(s) << 32) | (unsigned)k;
        best = (key < best) ? key : best;
      }
      if (lane == 0) atomicMin(&packed[q], best);
      if (lane == src) hm &= hm - 1;  // clear processed hit
    }
  }
}

// ---------------------------------------------------------------------------
// Exact fp32 rescore of (q,k) pairs (fallback path, R4-verified machinery).
// ---------------------------------------------------------------------------
__global__ __launch_bounds__(256) void exact_cand(const float* __restrict__ zT,
                                                  const float* __restrict__ cb,
                                                  const float* __restrict__ cbnorm,
                                                  const float* __restrict__ znorm,
                                                  const unsigned* __restrict__ pairs,
                                                  const int* __restrict__ paircount,
                                                  unsigned long long* __restrict__ packed) {
  const int cnt = min(*paircount, CAP_PAIRS);
  const int gw = (blockIdx.x * 256 + threadIdx.x) >> 6;
  const int nw = (gridDim.x * 256) >> 6;
  const int lane = threadIdx.x & 63;
  for (int p = gw; p < cnt; p += nw) {
    const unsigned qk = pairs[p];
    const int q = qk >> 13, k = qk & 8191;
    const float4 cv = ((const float4*)(cb + (size_t)k * FEAT))[lane];
    const float4 zv = ((const float4*)(zT + (size_t)q * FEAT))[lane];
    float d = __builtin_fmaf(zv.w, cv.w,
              __builtin_fmaf(zv.z, cv.z,
              __builtin_fmaf(zv.y, cv.y, __fmul_rn(zv.x, cv.x))));
#pragma unroll
    for (int dd = 1; dd < 64; dd <<= 1) d = __fadd_rn(d, __shfl_xor(d, dd, 64));
    const float s = __fadd_rn(__fadd_rn(__fmul_rn(-2.0f, d), znorm[q]), cbnorm[k]);
    if (lane == 0) {
      const unsigned long long key = ((unsigned long long)f2mono(s) << 32) | (unsigned)k;
      atomicMin(&packed[q], key);
    }
  }
}

// ---------------------------------------------------------------------------
// Gather: zq[b][c][hw] = cb[idx]; idx as float appended after zq.
// ---------------------------------------------------------------------------
__global__ __launch_bounds__(256) void vq_gather(const float* __restrict__ cb,
                                                 const unsigned long long* __restrict__ packed,
                                                 float* __restrict__ out) {
  const int q0 = blockIdx.x * 64;
  const int nl = threadIdx.x & 63;
  const int cg = threadIdx.x >> 6;
  const int q = q0 + nl;
  const int kq = (int)((unsigned)packed[q] & 8191u);
  const int b = q >> 10, hw = q & 1023;
  const float4* cb4 = (const float4*)cb;
#pragma unroll
  for (int t = 0; t < 16; ++t) {
    const int cc = cg + t * 4;
    const float4 v = cb4[kq * 64 + cc];
    const int base = b * (FEAT * 1024) + (cc * 4) * 1024 + hw;
    out[base] = v.x;
    out[base + 1024] = v.y;
    out[base + 2048] = v.z;
    out[base + 3072] = v.w;
  }
  if (threadIdx.x < 64) {
    const int qq = q0 + threadIdx.x;
    out[ZQ_ELEMS + qq] = (float)(int)((unsigned)packed[qq] & 8191u);
  }
}

extern "C" void kernel_launch(void* const* d_in, const int* in_sizes, int n_in,
                              void* d_out, int out_size, void* d_ws, size_t ws_size,
                              hipStream_t stream) {
  const float* z = (const float*)d_in[0];
  const float* cb = (const float*)d_in[1];
  char* w = (char*)d_ws;
  // ws layout: ~30 MiB fixed + 64 MiB group-min memo at MEMO_OFF
  char* At = w;                                            // 8 MB
  char* Bt = w + 8388608;                                  // 4 MB
  float* zT = (float*)(w + 12582912);                      // 16 MB
  float* cbnorm = (float*)(w + 29360128);                  // 32 KB
  float* znorm = (float*)(w + 29392896);                   // 64 KB
  unsigned* gmin = (unsigned*)(w + 29458432);              // 64 KB
  int* paircount = (int*)(w + 29523968);                   // 256 B
  unsigned* pairs = (unsigned*)(w + 29524224);             // 1 MB (fallback only)
  unsigned long long* packed = (unsigned long long*)(w + 30572800);  // 128 KB
  unsigned* memo = (unsigned*)(w + MEMO_OFF);              // 64 MiB fp16 group-mins

  const bool use_memo = ws_size >= (size_t)(MEMO_OFF + MEMO_BYTES);

  prep<<<PREP_BLOCKS, 256, 0, stream>>>(cb, z, cbnorm, At, zT, Bt,
                                        gmin, packed, paircount);
  if (use_memo) {
    gemm_pass1m<<<GEMM_BLKS + ZN_BLKS, 256, 0, stream>>>(At, Bt, cbnorm, gmin, memo, zT, znorm);
    scan_exact<<<2048, 256, 0, stream>>>(memo, gmin, zT, cb, cbnorm, znorm, packed);
  } else {
    znorm_zt<<<NQ / 16, 256, 0, stream>>>(zT, znorm);
    gemm_pass1<<<GEMM_BLKS, 256, 0, stream>>>(At, Bt, cbnorm, gmin);
    gemm_pass2<<<GEMM_BLKS, 256, 0, stream>>>(At, Bt, cbnorm, gmin, pairs, paircount);
    exact_cand<<<512, 256, 0, stream>>>(zT, cb, cbnorm, znorm, pairs, paircount, packed);
  }
  vq_gather<<<NQ / 64, 256, 0, stream>>>(cb, packed, (float*)d_out);
}